// Round 1
// baseline (203.831 us; speedup 1.0000x reference)
//
#include <hip/hip_runtime.h>
#include <math.h>

#define H 64
// ws layout (floats):
//   [0..63]    z_hist (LSTM final h)
//   [64..319]  64 x float4 fuse params: {base, sc0, sc1, w2}
//   [320..]    edge partials (eb*64), then node partials (nb*64)
#define WS_H 0
#define WS_FUSE 64
#define WS_PART 320

// ---------------- encoder helper: relu(X @ W + b) partial column-sums ----------------
template<int K>
__device__ void encode_rows(const float* __restrict__ X, const float* __restrict__ W,
                            const float* __restrict__ bias, int nrows,
                            int blk, int nblk, float* __restrict__ out, int tid)
{
    float acc[H];
#pragma unroll
    for (int j = 0; j < H; ++j) acc[j] = 0.f;

    for (int r = blk * 256 + tid; r < nrows; r += nblk * 256) {
        float x[K];
#pragma unroll
        for (int k = 0; k < K; ++k) x[k] = X[r * K + k];
#pragma unroll
        for (int j = 0; j < H; ++j) {
            float t = bias[j];
#pragma unroll
            for (int k = 0; k < K; ++k) t += x[k] * W[k * H + j];
            acc[j] += fmaxf(t, 0.f);
        }
    }

    // deterministic block reduction: wave butterfly, then cross-wave via LDS
    int lane = tid & 63;
    int w = tid >> 6;
    __shared__ float sred[4][H];
#pragma unroll
    for (int j = 0; j < H; ++j) {
        float v = acc[j];
#pragma unroll
        for (int off = 32; off > 0; off >>= 1) v += __shfl_xor(v, off);
        if (lane == 0) sred[w][j] = v;
    }
    __syncthreads();
    if (tid < H) out[tid] = (sred[0][tid] + sred[1][tid]) + (sred[2][tid] + sred[3][tid]);
}

// ---------------- kernel A: block 0 = LSTM, blocks 1..eb = edge, rest = node ----------------
__global__ __launch_bounds__(256)
void k_encode_lstm(const float* __restrict__ node_feats,
                   const float* __restrict__ edge_feats,
                   const float* __restrict__ hist,
                   const float* __restrict__ node_W, const float* __restrict__ node_b,
                   const float* __restrict__ edge_W, const float* __restrict__ edge_b,
                   const float* __restrict__ Wih, const float* __restrict__ Whh,
                   const float* __restrict__ bih, const float* __restrict__ bhh,
                   int Nn, int Ne, int T, int eb, int nb,
                   float* __restrict__ ws)
{
    int tid = threadIdx.x;
    int b = blockIdx.x;

    if (b == 0) {
        // ---- LSTM, 256 threads: thread j owns gate row j (order i,f,g,o) ----
        __shared__ float h_sh[H];
        __shared__ float g_sh[4 * H];
        int j = tid;
        float wih0 = Wih[j * 3 + 0], wih1 = Wih[j * 3 + 1], wih2 = Wih[j * 3 + 2];
        float bsum = bih[j] + bhh[j];
        float whh[H];
#pragma unroll
        for (int k = 0; k < H; ++k) whh[k] = Whh[j * H + k];
        if (tid < H) h_sh[tid] = 0.f;
        float c = 0.f;
        __syncthreads();

        for (int t = 0; t < T; ++t) {
            float x0 = hist[t * 3 + 0], x1 = hist[t * 3 + 1], x2 = hist[t * 3 + 2];
            float a0 = 0.f, a1 = 0.f, a2 = 0.f, a3 = 0.f;
#pragma unroll
            for (int k = 0; k < H; k += 4) {
                a0 += whh[k + 0] * h_sh[k + 0];
                a1 += whh[k + 1] * h_sh[k + 1];
                a2 += whh[k + 2] * h_sh[k + 2];
                a3 += whh[k + 3] * h_sh[k + 3];
            }
            float acc = bsum + wih0 * x0 + wih1 * x1 + wih2 * x2 + ((a0 + a1) + (a2 + a3));
            g_sh[j] = acc;
            __syncthreads();
            if (tid < H) {
                float ig = 1.f / (1.f + expf(-g_sh[tid]));
                float fg = 1.f / (1.f + expf(-g_sh[H + tid]));
                float gg = tanhf(g_sh[2 * H + tid]);
                float og = 1.f / (1.f + expf(-g_sh[3 * H + tid]));
                c = fg * c + ig * gg;
                h_sh[tid] = og * tanhf(c);
            }
            __syncthreads();
        }
        if (tid < H) ws[WS_H + tid] = h_sh[tid];
    } else if (b <= eb) {
        encode_rows<5>(edge_feats, edge_W, edge_b, Ne, b - 1, eb,
                       ws + WS_PART + (size_t)(b - 1) * H, tid);
    } else {
        encode_rows<2>(node_feats, node_W, node_b, Nn, b - 1 - eb, nb,
                       ws + WS_PART + (size_t)(eb + (b - 1 - eb)) * H, tid);
    }
}

// ---------------- kernel B: reduce partials, build ctx, precompute fuse params ----------------
__global__ __launch_bounds__(256)
void k_finalize(const float* __restrict__ fuse_W1, const float* __restrict__ fuse_b1,
                const float* __restrict__ fuse_W2,
                float inv_n, float inv_e, float inv_denom,
                int eb, int nb, float* __restrict__ ws)
{
    int tid = threadIdx.x;
    int j = tid & 63, q = tid >> 6;
    __shared__ float ctx[3 * H];
    __shared__ float tmpe[4][H];
    __shared__ float tmpn[4][H];

    float se = 0.f;
    for (int b = q; b < eb; b += 4) se += ws[WS_PART + (size_t)b * H + j];
    tmpe[q][j] = se;
    float sn = 0.f;
    for (int b = q; b < nb; b += 4) sn += ws[WS_PART + (size_t)(eb + b) * H + j];
    tmpn[q][j] = sn;
    __syncthreads();

    if (tid < H) {
        ctx[tid]         = ((tmpn[0][tid] + tmpn[1][tid]) + (tmpn[2][tid] + tmpn[3][tid])) * inv_n;
        ctx[H + tid]     = ((tmpe[0][tid] + tmpe[1][tid]) + (tmpe[2][tid] + tmpe[3][tid])) * inv_e;
        ctx[2 * H + tid] = ws[WS_H + tid];
    }
    __syncthreads();

    if (tid < H) {
        float bse = fuse_b1[tid];
        for (int k = 0; k < 3 * H; ++k) bse += ctx[k] * fuse_W1[k * H + tid];
        float4 v;
        v.x = bse;
        v.y = fuse_W1[192 * H + tid] * inv_denom;
        v.z = fuse_W1[193 * H + tid] * inv_denom;
        v.w = fuse_W2[tid];
        ((float4*)(ws + WS_FUSE))[tid] = v;
    }
}

// ---------------- kernel C: per-pair fused MLP score ----------------
__global__ __launch_bounds__(256)
void k_fuse(const int* __restrict__ pairs, const float* __restrict__ fuse_b2,
            const float* __restrict__ ws, float* __restrict__ out, int P)
{
    __shared__ float4 sf[H];
    int tid = threadIdx.x;
    if (tid < H) sf[tid] = ((const float4*)(ws + WS_FUSE))[tid];
    __syncthreads();

    int i = blockIdx.x * 256 + tid;
    if (i >= P) return;
    int2 pr = ((const int2*)pairs)[i];
    float p0 = (float)pr.x, p1 = (float)pr.y;
    float s = fuse_b2[0];
#pragma unroll
    for (int j = 0; j < H; ++j) {
        float4 v = sf[j];
        float h = v.x + p0 * v.y + p1 * v.z;
        s += fmaxf(h, 0.f) * v.w;
    }
    out[i] = s;
}

extern "C" void kernel_launch(void* const* d_in, const int* in_sizes, int n_in,
                              void* d_out, int out_size, void* d_ws, size_t ws_size,
                              hipStream_t stream) {
    const float* node_feats = (const float*)d_in[0];
    const float* edge_feats = (const float*)d_in[1];
    const float* hist       = (const float*)d_in[2];
    const int*   pairs      = (const int*)d_in[3];
    // d_in[4] = N scalar (== node row count)
    const float* node_W = (const float*)d_in[5];
    const float* node_b = (const float*)d_in[6];
    const float* edge_W = (const float*)d_in[7];
    const float* edge_b = (const float*)d_in[8];
    const float* Wih    = (const float*)d_in[9];
    const float* Whh    = (const float*)d_in[10];
    const float* bih    = (const float*)d_in[11];
    const float* bhh    = (const float*)d_in[12];
    const float* W1     = (const float*)d_in[13];
    const float* b1     = (const float*)d_in[14];
    const float* W2     = (const float*)d_in[15];
    const float* b2     = (const float*)d_in[16];

    int Nn = in_sizes[0] / 2;
    int Ne = in_sizes[1] / 5;
    int T  = in_sizes[2] / 3;
    int P  = in_sizes[3] / 2;

    // pick partial-block counts to fit workspace
    int eb = 512, nb = 32;
    while ((size_t)(WS_PART + (eb + nb) * H) * sizeof(float) > ws_size && eb > 8) {
        eb >>= 1; if (nb > 4) nb >>= 1;
    }

    float inv_n = (float)(1.0 / (double)Nn);
    float inv_e = (float)(1.0 / (double)Ne);
    float denomf = (float)(Nn - 1) + 1e-9f;
    float inv_denom = 1.0f / denomf;

    float* ws = (float*)d_ws;

    k_encode_lstm<<<1 + eb + nb, 256, 0, stream>>>(
        node_feats, edge_feats, hist, node_W, node_b, edge_W, edge_b,
        Wih, Whh, bih, bhh, Nn, Ne, T, eb, nb, ws);

    k_finalize<<<1, 256, 0, stream>>>(W1, b1, W2, inv_n, inv_e, inv_denom, eb, nb, ws);

    int blocksC = (P + 255) / 256;
    k_fuse<<<blocksC, 256, 0, stream>>>(pairs, b2, ws, (float*)d_out, P);
}

// Round 2
// 144.476 us; speedup vs baseline: 1.4108x; 1.4108x over previous
//
#include <hip/hip_runtime.h>
#include <math.h>

#define H 64
// ws layout (floats):
//   [0..63]    z_hist (LSTM final h)
//   [64..319]  64 x float4 fuse params: {base, sc0, sc1, w2}
//   [320..]    edge partials (eb*64), then node partials (nb*64)
#define WS_H 0
#define WS_FUSE 64
#define WS_PART 320
#define LOG2E 1.4426950408889634f

__device__ __forceinline__ float fast_sigmoid(float x) {
    float e = exp2f(-LOG2E * x);
    return __builtin_amdgcn_rcpf(1.f + e);
}
__device__ __forceinline__ float fast_tanh(float x) {
    x = fminf(fmaxf(x, -9.f), 9.f);
    float e = exp2f((2.f * LOG2E) * x);
    return (e - 1.f) * __builtin_amdgcn_rcpf(e + 1.f);
}

// ---------------- encoder: relu(X @ W + b) partial column-sums ----------------
// W/bias in registers (16-col slice per thread), X tiled through LDS (coalesced).
template<int K>
__device__ void encode_rows2(const float* __restrict__ X, const float* __restrict__ Wg,
                             const float* __restrict__ bias, int nrows,
                             int blk, int nblk, float* __restrict__ out, int tid)
{
    constexpr int TR = 512;                 // rows per LDS tile
    __shared__ __align__(16) float xs[TR * K];
    int lane = tid & 63;
    int j0 = (tid >> 6) * 16;               // 16-column slice per wave
    float w[K][16], bi[16], acc[16];
#pragma unroll
    for (int k = 0; k < K; ++k)
#pragma unroll
        for (int jj = 0; jj < 16; ++jj) w[k][jj] = Wg[k * H + j0 + jj];
#pragma unroll
    for (int jj = 0; jj < 16; ++jj) { bi[jj] = bias[j0 + jj]; acc[jj] = 0.f; }

    int ntiles = (nrows + TR - 1) / TR;
    for (int tile = blk; tile < ntiles; tile += nblk) {
        size_t base = (size_t)tile * TR;
        int cnt = nrows - (int)base; if (cnt > TR) cnt = TR;
        int ne = cnt * K;
        __syncthreads();                    // protect xs reuse across tiles
        const float* Xb = X + base * K;
        int n4 = ne >> 2;
        for (int idx = tid; idx < n4; idx += 256)
            ((float4*)xs)[idx] = ((const float4*)Xb)[idx];
        for (int idx = (n4 << 2) + tid; idx < ne; idx += 256)
            xs[idx] = Xb[idx];
        __syncthreads();
#pragma unroll
        for (int i = 0; i < TR / 64; ++i) {
            int r = i * 64 + lane;          // stride-K LDS reads: 5 & 2 coprime-ish with 32 -> ok
            if (r < cnt) {
                float x[K];
#pragma unroll
                for (int k = 0; k < K; ++k) x[k] = xs[r * K + k];
#pragma unroll
                for (int jj = 0; jj < 16; ++jj) {
                    float t = bi[jj];
#pragma unroll
                    for (int k = 0; k < K; ++k) t = fmaf(x[k], w[k][jj], t);
                    acc[jj] += fmaxf(t, 0.f);
                }
            }
        }
    }
    // per-wave butterfly reduce (waves own disjoint 16-col slices)
#pragma unroll
    for (int jj = 0; jj < 16; ++jj) {
        float v = acc[jj];
#pragma unroll
        for (int off = 32; off; off >>= 1) v += __shfl_xor(v, off);
        if (lane == jj) out[j0 + jj] = v;
    }
}

// ---------------- kernel A: block 0 = LSTM, blocks 1..eb = edge, rest = node ----------------
__global__ __launch_bounds__(256)
void k_encode_lstm(const float* __restrict__ node_feats,
                   const float* __restrict__ edge_feats,
                   const float* __restrict__ hist,
                   const float* __restrict__ node_W, const float* __restrict__ node_b,
                   const float* __restrict__ edge_W, const float* __restrict__ edge_b,
                   const float* __restrict__ Wih, const float* __restrict__ Whh,
                   const float* __restrict__ bih, const float* __restrict__ bhh,
                   int Nn, int Ne, int T, int eb, int nb,
                   float* __restrict__ ws)
{
    int tid = threadIdx.x;
    int b = blockIdx.x;

    if (b == 0) {
        // ---- LSTM: 4 waves; wave w = gate type w (i,f,g,o); lane j = h index ----
        __builtin_amdgcn_s_setprio(1);      // protect the serial chain from co-resident encoder waves
        __shared__ float hcop[4][H];        // per-wave private h copy
        __shared__ __align__(16) float4 actx[2][H]; // parity-double-buffered act exchange
        __shared__ float hist_s[640];
        int w = tid >> 6, j = tid & 63;
        int row = tid;                      // gate row = w*64 + j == tid
        float whh[H];
#pragma unroll
        for (int k = 0; k < H; k += 4) {
            float4 v = *(const float4*)(Whh + row * H + k);
            whh[k] = v.x; whh[k+1] = v.y; whh[k+2] = v.z; whh[k+3] = v.w;
        }
        float wih0 = Wih[row*3+0], wih1 = Wih[row*3+1], wih2 = Wih[row*3+2];
        float bsum = bih[row] + bhh[row];
        for (int idx = tid; idx < T * 3; idx += 256) hist_s[idx] = hist[idx];
        hcop[w][j] = 0.f;
        float c = 0.f, h = 0.f;
        __syncthreads();

        for (int t = 0; t < T; ++t) {
            float x0 = hist_s[3*t], x1 = hist_s[3*t+1], x2 = hist_s[3*t+2];
            float g = fmaf(wih0, x0, fmaf(wih1, x1, fmaf(wih2, x2, bsum)));
            float a0 = 0.f, a1 = 0.f, a2 = 0.f, a3 = 0.f;
            const float4* hv = (const float4*)hcop[w];  // own-wave copy: no barrier needed
#pragma unroll
            for (int k4 = 0; k4 < H / 4; ++k4) {
                float4 hh = hv[k4];
                a0 = fmaf(whh[4*k4+0], hh.x, a0);
                a1 = fmaf(whh[4*k4+1], hh.y, a1);
                a2 = fmaf(whh[4*k4+2], hh.z, a2);
                a3 = fmaf(whh[4*k4+3], hh.w, a3);
            }
            g += (a0 + a1) + (a2 + a3);
            float av = (w == 2) ? fast_tanh(g) : fast_sigmoid(g); // wave-uniform branch
            ((float*)&actx[t & 1][j])[w] = av;
            __syncthreads();                 // the ONLY barrier per step
            float4 a = actx[t & 1][j];       // (i,f,g,o) activated
            c = fmaf(a.y, c, a.x * a.z);
            h = a.w * fast_tanh(c);
            hcop[w][j] = h;                  // own-wave write; in-order LDS pipe
        }
        if (w == 0) ws[WS_H + j] = h;
    } else if (b <= eb) {
        encode_rows2<5>(edge_feats, edge_W, edge_b, Ne, b - 1, eb,
                        ws + WS_PART + (size_t)(b - 1) * H, tid);
    } else {
        encode_rows2<2>(node_feats, node_W, node_b, Nn, b - 1 - eb, nb,
                        ws + WS_PART + (size_t)(eb + (b - 1 - eb)) * H, tid);
    }
}

// ---------------- kernel B: reduce partials, build ctx, precompute fuse params ----------------
__global__ __launch_bounds__(1024)
void k_finalize(const float* __restrict__ W1, const float* __restrict__ b1,
                const float* __restrict__ W2,
                float inv_n, float inv_e, float inv_denom,
                int eb, int nb, float* __restrict__ ws)
{
    int tid = threadIdx.x;
    int j = tid & 63, q = tid >> 6;          // q in 0..15
    __shared__ float tmpe[16][H], tmpn[16][H];
    __shared__ float ctx[3 * H];
    __shared__ float pt[16][H];

    float se = 0.f;
    for (int b = q; b < eb; b += 16) se += ws[WS_PART + (size_t)b * H + j];
    tmpe[q][j] = se;
    float sn = 0.f;
    for (int b = q; b < nb; b += 16) sn += ws[WS_PART + (size_t)(eb + b) * H + j];
    tmpn[q][j] = sn;
    __syncthreads();

    if (tid < H) {
        float s1 = 0.f, s2 = 0.f;
#pragma unroll
        for (int r = 0; r < 16; ++r) { s1 += tmpn[r][tid]; s2 += tmpe[r][tid]; }
        ctx[tid]         = s1 * inv_n;
        ctx[H + tid]     = s2 * inv_e;
        ctx[2 * H + tid] = ws[WS_H + tid];
    }
    __syncthreads();

    // 192x64 matvec, k split across q
    float p = 0.f;
#pragma unroll
    for (int kk = 0; kk < 12; ++kk) {
        int k = q * 12 + kk;
        p = fmaf(ctx[k], W1[(size_t)k * H + j], p);
    }
    pt[q][j] = p;
    __syncthreads();

    if (tid < H) {
        float bse = b1[tid];
#pragma unroll
        for (int r = 0; r < 16; ++r) bse += pt[r][tid];
        float4 v;
        v.x = bse;
        v.y = W1[(size_t)192 * H + tid] * inv_denom;
        v.z = W1[(size_t)193 * H + tid] * inv_denom;
        v.w = W2[tid];
        ((float4*)(ws + WS_FUSE))[tid] = v;
    }
}

// ---------------- kernel C: per-pair fused MLP score, 4 pairs/thread ----------------
__global__ __launch_bounds__(256)
void k_fuse(const int* __restrict__ pairs, const float* __restrict__ fb2,
            const float* __restrict__ ws, float* __restrict__ out, int P)
{
    __shared__ __align__(16) float4 sf[H];
    int tid = threadIdx.x;
    if (tid < H) sf[tid] = ((const float4*)(ws + WS_FUSE))[tid];
    __syncthreads();

    int i0 = blockIdx.x * 1024 + tid;
    float bias = fb2[0];
    float p0[4], p1[4], s[4];
#pragma unroll
    for (int q = 0; q < 4; ++q) {
        int i = i0 + q * 256;
        int2 pr = (i < P) ? ((const int2*)pairs)[i] : make_int2(0, 0);
        p0[q] = (float)pr.x; p1[q] = (float)pr.y; s[q] = bias;
    }
#pragma unroll
    for (int j = 0; j < H; ++j) {
        float4 v = sf[j];
#pragma unroll
        for (int q = 0; q < 4; ++q) {
            float hh = fmaf(p1[q], v.z, fmaf(p0[q], v.y, v.x));
            s[q] = fmaf(fmaxf(hh, 0.f), v.w, s[q]);
        }
    }
#pragma unroll
    for (int q = 0; q < 4; ++q) {
        int i = i0 + q * 256;
        if (i < P) out[i] = s[q];
    }
}

extern "C" void kernel_launch(void* const* d_in, const int* in_sizes, int n_in,
                              void* d_out, int out_size, void* d_ws, size_t ws_size,
                              hipStream_t stream) {
    const float* node_feats = (const float*)d_in[0];
    const float* edge_feats = (const float*)d_in[1];
    const float* hist       = (const float*)d_in[2];
    const int*   pairs      = (const int*)d_in[3];
    // d_in[4] = N scalar (== node row count)
    const float* node_W = (const float*)d_in[5];
    const float* node_b = (const float*)d_in[6];
    const float* edge_W = (const float*)d_in[7];
    const float* edge_b = (const float*)d_in[8];
    const float* Wih    = (const float*)d_in[9];
    const float* Whh    = (const float*)d_in[10];
    const float* bih    = (const float*)d_in[11];
    const float* bhh    = (const float*)d_in[12];
    const float* W1     = (const float*)d_in[13];
    const float* b1     = (const float*)d_in[14];
    const float* W2     = (const float*)d_in[15];
    const float* b2     = (const float*)d_in[16];

    int Nn = in_sizes[0] / 2;
    int Ne = in_sizes[1] / 5;
    int T  = in_sizes[2] / 3;
    int P  = in_sizes[3] / 2;

    // partial-block counts (fit workspace)
    int eb = 1024, nb = 64;
    while ((size_t)(WS_PART + (eb + nb) * H) * sizeof(float) > ws_size && eb > 8) {
        eb >>= 1; if (nb > 4) nb >>= 1;
    }

    float inv_n = (float)(1.0 / (double)Nn);
    float inv_e = (float)(1.0 / (double)Ne);
    float denomf = (float)(Nn - 1) + 1e-9f;
    float inv_denom = 1.0f / denomf;

    float* ws = (float*)d_ws;

    k_encode_lstm<<<1 + eb + nb, 256, 0, stream>>>(
        node_feats, edge_feats, hist, node_W, node_b, edge_W, edge_b,
        Wih, Whh, bih, bhh, Nn, Ne, T, eb, nb, ws);

    k_finalize<<<1, 1024, 0, stream>>>(W1, b1, W2, inv_n, inv_e, inv_denom, eb, nb, ws);

    int blocksC = (P + 1023) / 1024;
    k_fuse<<<blocksC, 256, 0, stream>>>(pairs, b2, ws, (float*)d_out, P);
}